// Round 6
// baseline (125.684 us; speedup 1.0000x reference)
//
#include <hip/hip_runtime.h>
#include <stdint.h>

#define Bb 32
#define Ss 2048
#define Dd 128
#define KVB 64

typedef __attribute__((ext_vector_type(2))) float f32x2;
typedef __attribute__((ext_vector_type(4))) float f32x4;
typedef __attribute__((ext_vector_type(16))) float f32x16;
typedef __attribute__((ext_vector_type(8))) _Float16 f16x8;
typedef __attribute__((ext_vector_type(2))) __fp16 fp16x2;
typedef __attribute__((ext_vector_type(8))) unsigned short u16x8;
typedef __attribute__((ext_vector_type(4))) unsigned short u16x4;

union F16_8 { u16x8 u; uint32_t w[4]; f16x8 h; };
union F16_4 { u16x4 u; uint32_t w[2]; };

__device__ __forceinline__ uint32_t pk2(float a, float b) {   // packed f32->f16 RTZ
    union { fp16x2 h; uint32_t u; } v;
    v.h = __builtin_amdgcn_cvt_pkrtz(a, b);
    return v.u;
}

__global__ __launch_bounds__(256) __attribute__((amdgpu_waves_per_eu(2, 2)))
void attn_fwd(const float* __restrict__ Q,
              const float* __restrict__ K,
              const float* __restrict__ V,
              const int* __restrict__ M,
              float* __restrict__ O) {
    __shared__ unsigned short K_lds[KVB * 128];   // 16 KB, [key][d] fp16, XOR-swizzled
    __shared__ unsigned short VT_lds[128 * 64];   // 16 KB, [d][key] fp16, XOR-swizzled
    __shared__ float maskadd[KVB];
    __shared__ unsigned short IDX[Ss];            // 4 KB, compacted active-key indices
    __shared__ int scan_s[256];

    const int tid = threadIdx.x;
    const int w   = tid >> 6;
    const int l   = tid & 63;
    const int q31 = l & 31;       // this lane's q-column (and LDS row index)
    const int hi  = l >> 5;

    const int bid   = blockIdx.x;
    const int batch = (bid & 7) * 4 + (bid >> 7);   // XCD-aware, bijective
    const int qtile = (bid >> 3) & 15;

    const size_t qrow0  = (size_t)batch * Ss + qtile * 128 + w * 32;
    const size_t kvbase = (size_t)batch * Ss * Dd;
    const size_t mbase  = (size_t)batch * Ss;

    // ---- per-block mask compaction (mask is [B,1,S]: batch-uniform over queries) ----
    // Each thread owns 8 consecutive keys; block-wide scan -> compact active keys to IDX.
    int loc[8]; int csum = 0;
    {
        const int4* m4 = (const int4*)(M + mbase + tid * 8);
        int4 a = m4[0], b = m4[1];
        loc[0] = (a.x != 0); loc[1] = (a.y != 0); loc[2] = (a.z != 0); loc[3] = (a.w != 0);
        loc[4] = (b.x != 0); loc[5] = (b.y != 0); loc[6] = (b.z != 0); loc[7] = (b.w != 0);
#pragma unroll
        for (int j = 0; j < 8; ++j) csum += loc[j];
    }
    scan_s[tid] = csum;
    __syncthreads();
    for (int off = 1; off < 256; off <<= 1) {     // Hillis-Steele inclusive scan
        int v = scan_s[tid];
        int u = (tid >= off) ? scan_s[tid - off] : 0;
        __syncthreads();
        scan_s[tid] = v + u;
        __syncthreads();
    }
    const int count = scan_s[255];                // active keys in this batch
    const int ntile = (count + KVB - 1) >> 6;
    {
        int base = scan_s[tid] - csum;            // exclusive prefix
#pragma unroll
        for (int j = 0; j < 8; ++j)
            if (loc[j]) IDX[base++] = (unsigned short)(tid * 8 + j);
        for (int p = count + tid; p < (ntile << 6); p += 256) IDX[p] = 0;  // pad (masked via maskadd)
    }
    __syncthreads();

    // ---- staging geometry ----
    const int krow = tid >> 4;            // K: rows krow+16*it
    const int kcol = (tid & 15) << 3;     // K: 8 floats
    const int vi   = tid & 15;            // V: d-pair base (rows 2vi+p+32j)
    const int vk   = (tid >> 4) << 2;     // V: 4 keys

    f32x4 ka[4], kb[4];                   // K tile in flight
    f32x2 vv[4][4];                       // V tile in flight [j][ko]

    auto issueK = [&](int kv) {
#pragma unroll
        for (int it = 0; it < 4; ++it) {
            const int r = IDX[kv + krow + it * 16];     // gathered active-key row
            const float* s = K + kvbase + (size_t)r * Dd + kcol;
            ka[it] = *(const f32x4*)s;
            kb[it] = *(const f32x4*)(s + 4);
        }
    };
    auto writeK = [&](int kv) {
#pragma unroll
        for (int it = 0; it < 4; ++it) {
            int row = krow + it * 16;
            F16_8 t;
            t.w[0] = pk2(ka[it][0], ka[it][1]);
            t.w[1] = pk2(ka[it][2], ka[it][3]);
            t.w[2] = pk2(kb[it][0], kb[it][1]);
            t.w[3] = pk2(kb[it][2], kb[it][3]);
            *(u16x8*)&K_lds[(row * 128 + kcol) ^ ((row & 7) << 3)] = t.u;
        }
        if (tid < KVB) maskadd[tid] = (kv + tid < count) ? 0.f : -1e30f;   // pads only
    };
    auto issueV = [&](int kv) {
        int rr[4];
#pragma unroll
        for (int ko = 0; ko < 4; ++ko) rr[ko] = IDX[kv + vk + ko];
#pragma unroll
        for (int j = 0; j < 4; ++j)
#pragma unroll
            for (int ko = 0; ko < 4; ++ko)
                vv[j][ko] = *(const f32x2*)(V + kvbase + (size_t)rr[ko] * Dd + 2 * vi + 32 * j);
    };
    auto writeV = [&]() {
#pragma unroll
        for (int j = 0; j < 4; ++j)
#pragma unroll
            for (int p = 0; p < 2; ++p) {
                int row = 2 * vi + p + 32 * j;           // row&7 varies per lane -> conflict-free
                F16_4 t;
                t.w[0] = pk2(vv[j][0][p], vv[j][1][p]);
                t.w[1] = pk2(vv[j][2][p], vv[j][3][p]);
                *(u16x4*)&VT_lds[row * 64 + (vk ^ ((row & 7) << 3))] = t.u;
            }
    };

    // ones A-fragment (rows 0..7 = 1.0) for MFMA-computed l
    F16_8 ones;
    {
        uint32_t ow = (q31 < 8) ? 0x3C003C00u : 0u;
        ones.w[0] = ow; ones.w[1] = ow; ones.w[2] = ow; ones.w[3] = ow;
    }

    const f32x16 z16 = {0,0,0,0,0,0,0,0,0,0,0,0,0,0,0,0};
    f32x16 acco[4];                       // O^T: lane owns q=q31, rows = d (crow pattern)
#pragma unroll
    for (int dn = 0; dn < 4; ++dn) acco[dn] = z16;
    f32x16 accl = z16;                    // l in element 0
    float mrun = -1e4f;

    // ---- prologue: stage tile 0; Q frags (pre-scaled by log2 e) cover the latency ----
    const float LOG2E = 1.44269504088896340736f;
    if (ntile > 0) { issueK(0); issueV(0); }
    F16_8 qf[8];
#pragma unroll
    for (int ks = 0; ks < 8; ++ks) {
        const float* s = Q + (qrow0 + q31) * Dd + ks * 16 + hi * 8;
        f32x4 a = *(const f32x4*)s;
        f32x4 b = *(const f32x4*)(s + 4);
        qf[ks].w[0] = pk2(a[0] * LOG2E, a[1] * LOG2E);
        qf[ks].w[1] = pk2(a[2] * LOG2E, a[3] * LOG2E);
        qf[ks].w[2] = pk2(b[0] * LOG2E, b[1] * LOG2E);
        qf[ks].w[3] = pk2(b[2] * LOG2E, b[3] * LOG2E);
    }
    if (ntile > 0) {
        writeK(0); writeV();
        __syncthreads();
    }

    for (int t = 0; t < ntile; ++t) {
        if (t < ntile - 1) issueK((t + 1) * KVB);    // hides under QK+softmax

        // ---- S^T = K · Q^T : lane holds P^T[key crow(reg,hi)][q31] (log2 units) ----
        f32x16 accs[2];
        accs[0] = z16; accs[1] = z16;
#pragma unroll
        for (int ks = 0; ks < 8; ++ks) {
#pragma unroll
            for (int n = 0; n < 2; ++n) {
                int row = n * 32 + q31;
                F16_8 kf;
                kf.u = *(const u16x8*)&K_lds[(row * 128 + ks * 16 + hi * 8) ^ ((row & 7) << 3)];
                accs[n] = __builtin_amdgcn_mfma_f32_32x32x16_f16(kf.h, qf[ks].h, accs[n], 0, 0, 0);
            }
        }

        // ---- additive pad-mask: only the final partial tile needs it ----
        if ((t == ntile - 1) && (count & 63)) {
#pragma unroll
            for (int n = 0; n < 2; ++n)
#pragma unroll
                for (int blk = 0; blk < 4; ++blk) {
                    f32x4 md = *(const f32x4*)&maskadd[n * 32 + blk * 8 + 4 * hi];
#pragma unroll
                    for (int r = 0; r < 4; ++r) accs[n][blk * 4 + r] += md[r];
                }
        }

        // ---- max: depth-5 tree ----
        float mx[16];
#pragma unroll
        for (int i = 0; i < 16; ++i) mx[i] = fmaxf(accs[0][i], accs[1][i]);
#pragma unroll
        for (int s = 8; s >= 1; s >>= 1)
#pragma unroll
            for (int i = 0; i < s; ++i) mx[i] = fmaxf(mx[i], mx[i + s]);
        float pmax = fmaxf(mx[0], __shfl_xor(mx[0], 32));

        // ---- online softmax, defer-max (T13); threshold 8 nats = 11.54 log2-units ----
        if (!__all(pmax - mrun <= 11.5409f)) {
            float mnew = fmaxf(mrun, pmax);
            float sc = __builtin_amdgcn_exp2f(mrun - mnew);
#pragma unroll
            for (int dn = 0; dn < 4; ++dn)
#pragma unroll
                for (int i = 0; i < 16; ++i) acco[dn][i] *= sc;
            accl[0] *= sc;
            mrun = mnew;
        }

#pragma unroll
        for (int n = 0; n < 2; ++n)
#pragma unroll
            for (int i = 0; i < 16; ++i) accs[n][i] = __builtin_amdgcn_exp2f(accs[n][i] - mrun);

        // ---- P^T -> B-fragments via permlane32_swap (T12) ----
        F16_8 pa[4];
#pragma unroll
        for (int ks = 0; ks < 4; ++ks) {
            int n  = ks >> 1;
            int b4 = (ks & 1) * 8;
            uint32_t x0 = pk2(accs[n][b4 + 0], accs[n][b4 + 1]);
            uint32_t x1 = pk2(accs[n][b4 + 2], accs[n][b4 + 3]);
            uint32_t y0 = pk2(accs[n][b4 + 4], accs[n][b4 + 5]);
            uint32_t y1 = pk2(accs[n][b4 + 6], accs[n][b4 + 7]);
            asm volatile("v_permlane32_swap_b32 %0, %1" : "+v"(x0), "+v"(y0));
            asm volatile("v_permlane32_swap_b32 %0, %1" : "+v"(x1), "+v"(y1));
            pa[ks].w[0] = x0;   // keys ks*16+hi*8 + {0,1}
            pa[ks].w[1] = x1;   // + {2,3}
            pa[ks].w[2] = y0;   // + {4,5}
            pa[ks].w[3] = y1;   // + {6,7}
        }

        __syncthreads();                       // K_lds + maskadd reads of tile t done
        if (t < ntile - 1) { writeK((t + 1) * KVB); issueV((t + 1) * KVB); }

        // ---- O^T += V^T · P^T (all lane-q-local) ----
#pragma unroll
        for (int dn = 0; dn < 4; ++dn) {
            int row = dn * 32 + q31;
#pragma unroll
            for (int ks = 0; ks < 4; ++ks) {
                F16_8 vf;
                vf.u = *(const u16x8*)&VT_lds[row * 64 + ((ks * 16 + hi * 8) ^ ((row & 7) << 3))];
                acco[dn] = __builtin_amdgcn_mfma_f32_32x32x16_f16(vf.h, pa[ks].h, acco[dn], 0, 0, 0);
            }
        }
#pragma unroll
        for (int ks = 0; ks < 4; ++ks)
            accl = __builtin_amdgcn_mfma_f32_32x32x16_f16(ones.h, pa[ks].h, accl, 0, 0, 0);

        __syncthreads();                       // VT_lds reads of tile t done
        if (t < ntile - 1) writeV();
    }

    // ---- epilogue ----
    float lv   = accl[0];
    float linv = lv > 0.f ? 1.0f / lv : 0.f;   // count==0 -> l==0 -> O=0 (matches reference)
    float* orow = O + (qrow0 + q31) * Dd;
#pragma unroll
    for (int dn = 0; dn < 4; ++dn)
#pragma unroll
        for (int rg = 0; rg < 4; ++rg) {
            f32x4 o;
            o[0] = acco[dn][rg * 4 + 0] * linv;
            o[1] = acco[dn][rg * 4 + 1] * linv;
            o[2] = acco[dn][rg * 4 + 2] * linv;
            o[3] = acco[dn][rg * 4 + 3] * linv;
            *(f32x4*)(orow + dn * 32 + rg * 8 + 4 * hi) = o;
        }
}

extern "C" void kernel_launch(void* const* d_in, const int* in_sizes, int n_in,
                              void* d_out, int out_size, void* d_ws, size_t ws_size,
                              hipStream_t stream) {
    const float* Q = (const float*)d_in[0];
    const float* K = (const float*)d_in[1];
    const float* V = (const float*)d_in[2];
    const int*   M = (const int*)d_in[3];
    float* O = (float*)d_out;
    dim3 grid(Bb * (Ss / 128));   // 512 blocks
    dim3 block(256);
    attn_fwd<<<grid, block, 0, stream>>>(Q, K, V, M, O);
}

// Round 7
// 75.753 us; speedup vs baseline: 1.6591x; 1.6591x over previous
//
#include <hip/hip_runtime.h>
#include <stdint.h>

#define Bb 32
#define Ss 2048
#define Dd 128
#define KVB 64
#define NIT (Ss / KVB)   // 32

typedef __attribute__((ext_vector_type(2))) float f32x2;
typedef __attribute__((ext_vector_type(4))) float f32x4;
typedef __attribute__((ext_vector_type(16))) float f32x16;
typedef __attribute__((ext_vector_type(8))) _Float16 f16x8;
typedef __attribute__((ext_vector_type(2))) __fp16 fp16x2;
typedef __attribute__((ext_vector_type(8))) unsigned short u16x8;
typedef __attribute__((ext_vector_type(4))) unsigned short u16x4;

union F16_8 { u16x8 u; uint32_t w[4]; f16x8 h; };
union F16_4 { u16x4 u; uint32_t w[2]; };

__device__ __forceinline__ uint32_t pk2(float a, float b) {   // packed f32->f16 RTZ
    union { fp16x2 h; uint32_t u; } v;
    v.h = __builtin_amdgcn_cvt_pkrtz(a, b);
    return v.u;
}

// ---------------- P1: per-batch mask scan -> IDXg, counts ----------------
__global__ __launch_bounds__(256)
void attn_compact_idx(const int* __restrict__ M, int* __restrict__ IDXg, int* __restrict__ CNT) {
    __shared__ int scan_s[256];
    const int b = blockIdx.x, tid = threadIdx.x;
    const int* m = M + (size_t)b * Ss + tid * 8;
    int loc[8]; int csum = 0;
    {
        int4 a = *(const int4*)m;
        int4 c = *(const int4*)(m + 4);
        loc[0] = (a.x != 0); loc[1] = (a.y != 0); loc[2] = (a.z != 0); loc[3] = (a.w != 0);
        loc[4] = (c.x != 0); loc[5] = (c.y != 0); loc[6] = (c.z != 0); loc[7] = (c.w != 0);
#pragma unroll
        for (int j = 0; j < 8; ++j) csum += loc[j];
    }
    scan_s[tid] = csum;
    __syncthreads();
    for (int off = 1; off < 256; off <<= 1) {     // Hillis-Steele inclusive scan
        int v = scan_s[tid];
        int u = (tid >= off) ? scan_s[tid - off] : 0;
        __syncthreads();
        scan_s[tid] = v + u;
        __syncthreads();
    }
    int base = scan_s[tid] - csum;                // exclusive prefix
    int* idx = IDXg + (size_t)b * Ss;
#pragma unroll
    for (int j = 0; j < 8; ++j)
        if (loc[j]) idx[base++] = tid * 8 + j;
    if (tid == 255) CNT[b] = scan_s[255];
}

// ---------------- P2: gather-compact K,V -> fp16 Kc,Vc (zero-padded to 64) ----------------
__global__ __launch_bounds__(256)
void attn_compact_copy(const float* __restrict__ K, const float* __restrict__ V,
                       const int* __restrict__ IDXg, const int* __restrict__ CNT,
                       unsigned short* __restrict__ Kc, unsigned short* __restrict__ Vc) {
    const int b = blockIdx.x >> 5, chunk = blockIdx.x & 31;
    const int count = CNT[b];
    const int ntpad = ((count + 63) >> 6) << 6;
    const int p0 = chunk * 64;
    if (p0 >= ntpad) return;
    const int tid  = threadIdx.x;
    const int rsub = tid >> 4;              // 16 rows in parallel
    const int colh = (tid & 15) * 8;        // 8 elems
    const int* idx = IDXg + (size_t)b * Ss;
    const size_t gbase = (size_t)b * Ss * Dd;
#pragma unroll
    for (int pass = 0; pass < 2; ++pass) {
        const float* src = pass ? V : K;
        unsigned short* dst = pass ? Vc : Kc;
#pragma unroll
        for (int it = 0; it < 4; ++it) {
            int s = p0 + rsub + it * 16;
            if (s >= ntpad) continue;
            F16_8 t;
            if (s < count) {
                const float* sp = src + gbase + (size_t)idx[s] * Dd + colh;
                f32x4 x = *(const f32x4*)sp;
                f32x4 y = *(const f32x4*)(sp + 4);
                t.w[0] = pk2(x[0], x[1]); t.w[1] = pk2(x[2], x[3]);
                t.w[2] = pk2(y[0], y[1]); t.w[3] = pk2(y[2], y[3]);
            } else {
                t.w[0] = 0u; t.w[1] = 0u; t.w[2] = 0u; t.w[3] = 0u;   // pad rows zeroed
            }
            *(u16x8*)(dst + gbase + (size_t)s * Dd + colh) = t.u;
        }
    }
}

// ---------------- main: R5 schedule, dense pre-converted fp16 K/V ----------------
__global__ __launch_bounds__(256) __attribute__((amdgpu_waves_per_eu(2, 2)))
void attn_fwd_c(const float* __restrict__ Q,
                const unsigned short* __restrict__ Kc,
                const unsigned short* __restrict__ Vc,
                const int* __restrict__ CNT,
                float* __restrict__ O) {
    __shared__ unsigned short K_lds[KVB * 128];   // 16 KB, [key][d] fp16, XOR-swizzled
    __shared__ unsigned short VT_lds[128 * 64];   // 16 KB, [d][key] fp16, XOR-swizzled
    __shared__ float maskadd[KVB];

    const int tid = threadIdx.x;
    const int w   = tid >> 6;
    const int l   = tid & 63;
    const int q31 = l & 31;
    const int hi  = l >> 5;

    const int bid   = blockIdx.x;
    const int batch = (bid & 7) * 4 + (bid >> 7);   // XCD-aware, bijective
    const int qtile = (bid >> 3) & 15;

    const size_t qrow0 = (size_t)batch * Ss + qtile * 128 + w * 32;
    const size_t kvb16 = (size_t)batch * Ss * Dd;   // u16 elems

    const int count = CNT[batch];
    const int ntile = (count + KVB - 1) >> 6;

    // ---- staging geometry ----
    const int krow  = tid >> 4;            // K: rows krow+16*it
    const int kcol8 = (tid & 15) << 3;     // K: 8 halves
    const int vi    = tid & 15;            // V: d-pair base (rows 2vi+p+32j)
    const int vk    = (tid >> 4) << 2;     // V: 4 keys

    u16x8    ka[4];                        // K tile in flight (16 VGPR)
    uint32_t vv[4][4];                     // V tile in flight [j][ko], 2 halves each (16 VGPR)

    auto issueK = [&](int kv) {
#pragma unroll
        for (int it = 0; it < 4; ++it)
            ka[it] = *(const u16x8*)(Kc + kvb16 + (size_t)(kv + krow + it * 16) * Dd + kcol8);
    };
    auto writeK = [&](int kv) {
#pragma unroll
        for (int it = 0; it < 4; ++it) {
            int row = krow + it * 16;
            *(u16x8*)&K_lds[(row * 128 + kcol8) ^ ((row & 7) << 3)] = ka[it];
        }
        if (tid < KVB) maskadd[tid] = (kv + tid < count) ? 0.f : -1e30f;
    };
    auto issueV = [&](int kv) {
#pragma unroll
        for (int j = 0; j < 4; ++j)
#pragma unroll
            for (int ko = 0; ko < 4; ++ko)
                vv[j][ko] = *(const uint32_t*)(Vc + kvb16 + (size_t)(kv + vk + ko) * Dd + 2 * vi + 32 * j);
    };
    auto writeV = [&]() {
#pragma unroll
        for (int j = 0; j < 4; ++j)
#pragma unroll
            for (int p = 0; p < 2; ++p) {
                int row = 2 * vi + p + 32 * j;           // row&7 varies per lane -> conflict-free
                F16_4 t;
                if (p == 0) {
                    t.w[0] = (vv[j][0] & 0xffffu) | (vv[j][1] << 16);
                    t.w[1] = (vv[j][2] & 0xffffu) | (vv[j][3] << 16);
                } else {
                    t.w[0] = (vv[j][0] >> 16) | (vv[j][1] & 0xffff0000u);
                    t.w[1] = (vv[j][2] >> 16) | (vv[j][3] & 0xffff0000u);
                }
                *(u16x4*)&VT_lds[row * 64 + (vk ^ ((row & 7) << 3))] = t.u;
            }
    };

    // ones A-fragment (rows 0..7 = 1.0) for MFMA-computed l
    F16_8 ones;
    {
        uint32_t ow = (q31 < 8) ? 0x3C003C00u : 0u;
        ones.w[0] = ow; ones.w[1] = ow; ones.w[2] = ow; ones.w[3] = ow;
    }

    const f32x16 z16 = {0,0,0,0,0,0,0,0,0,0,0,0,0,0,0,0};
    f32x16 acco[4];
#pragma unroll
    for (int dn = 0; dn < 4; ++dn) acco[dn] = z16;
    f32x16 accl = z16;
    float mrun = -1e4f;

    // ---- prologue ----
    const float LOG2E = 1.44269504088896340736f;
    if (ntile > 0) { issueK(0); issueV(0); }
    F16_8 qf[8];
#pragma unroll
    for (int ks = 0; ks < 8; ++ks) {
        const float* s = Q + (qrow0 + q31) * Dd + ks * 16 + hi * 8;
        f32x4 a = *(const f32x4*)s;
        f32x4 b = *(const f32x4*)(s + 4);
        qf[ks].w[0] = pk2(a[0] * LOG2E, a[1] * LOG2E);
        qf[ks].w[1] = pk2(a[2] * LOG2E, a[3] * LOG2E);
        qf[ks].w[2] = pk2(b[0] * LOG2E, b[1] * LOG2E);
        qf[ks].w[3] = pk2(b[2] * LOG2E, b[3] * LOG2E);
    }
    if (ntile > 0) {
        writeK(0); writeV();
        __syncthreads();
    }

    for (int t = 0; t < ntile; ++t) {
        if (t < ntile - 1) issueK((t + 1) * KVB);    // hides under QK+softmax

        // ---- S^T = K · Q^T (log2 units) ----
        f32x16 accs[2];
        accs[0] = z16; accs[1] = z16;
#pragma unroll
        for (int ks = 0; ks < 8; ++ks) {
#pragma unroll
            for (int n = 0; n < 2; ++n) {
                int row = n * 32 + q31;
                F16_8 kf;
                kf.u = *(const u16x8*)&K_lds[(row * 128 + ks * 16 + hi * 8) ^ ((row & 7) << 3)];
                accs[n] = __builtin_amdgcn_mfma_f32_32x32x16_f16(kf.h, qf[ks].h, accs[n], 0, 0, 0);
            }
        }

        // ---- pad-mask: only the final partial tile ----
        if ((t == ntile - 1) && (count & 63)) {
#pragma unroll
            for (int n = 0; n < 2; ++n)
#pragma unroll
                for (int blk = 0; blk < 4; ++blk) {
                    f32x4 md = *(const f32x4*)&maskadd[n * 32 + blk * 8 + 4 * hi];
#pragma unroll
                    for (int r = 0; r < 4; ++r) accs[n][blk * 4 + r] += md[r];
                }
        }

        // ---- max: depth-5 tree ----
        float mx[16];
#pragma unroll
        for (int i = 0; i < 16; ++i) mx[i] = fmaxf(accs[0][i], accs[1][i]);
#pragma unroll
        for (int s = 8; s >= 1; s >>= 1)
#pragma unroll
            for (int i = 0; i < s; ++i) mx[i] = fmaxf(mx[i], mx[i + s]);
        float pmax = fmaxf(mx[0], __shfl_xor(mx[0], 32));

        // ---- online softmax, defer-max; threshold 8 nats = 11.54 log2-units ----
        if (!__all(pmax - mrun <= 11.5409f)) {
            float mnew = fmaxf(mrun, pmax);
            float sc = __builtin_amdgcn_exp2f(mrun - mnew);
#pragma unroll
            for (int dn = 0; dn < 4; ++dn)
#pragma unroll
                for (int i = 0; i < 16; ++i) acco[dn][i] *= sc;
            accl[0] *= sc;
            mrun = mnew;
        }

#pragma unroll
        for (int n = 0; n < 2; ++n)
#pragma unroll
            for (int i = 0; i < 16; ++i) accs[n][i] = __builtin_amdgcn_exp2f(accs[n][i] - mrun);

        // ---- P^T -> B-fragments via permlane32_swap ----
        F16_8 pa[4];
#pragma unroll
        for (int ks = 0; ks < 4; ++ks) {
            int n  = ks >> 1;
            int b4 = (ks & 1) * 8;
            uint32_t x0 = pk2(accs[n][b4 + 0], accs[n][b4 + 1]);
            uint32_t x1 = pk2(accs[n][b4 + 2], accs[n][b4 + 3]);
            uint32_t y0 = pk2(accs[n][b4 + 4], accs[n][b4 + 5]);
            uint32_t y1 = pk2(accs[n][b4 + 6], accs[n][b4 + 7]);
            asm volatile("v_permlane32_swap_b32 %0, %1" : "+v"(x0), "+v"(y0));
            asm volatile("v_permlane32_swap_b32 %0, %1" : "+v"(x1), "+v"(y1));
            pa[ks].w[0] = x0; pa[ks].w[1] = x1; pa[ks].w[2] = y0; pa[ks].w[3] = y1;
        }

        __syncthreads();                       // K_lds + maskadd reads of tile t done
        if (t < ntile - 1) { writeK((t + 1) * KVB); issueV((t + 1) * KVB); }

        // ---- O^T += V^T · P^T ----
#pragma unroll
        for (int dn = 0; dn < 4; ++dn) {
            int row = dn * 32 + q31;
#pragma unroll
            for (int ks = 0; ks < 4; ++ks) {
                F16_8 vf;
                vf.u = *(const u16x8*)&VT_lds[row * 64 + ((ks * 16 + hi * 8) ^ ((row & 7) << 3))];
                acco[dn] = __builtin_amdgcn_mfma_f32_32x32x16_f16(vf.h, pa[ks].h, acco[dn], 0, 0, 0);
            }
        }
#pragma unroll
        for (int ks = 0; ks < 4; ++ks)
            accl = __builtin_amdgcn_mfma_f32_32x32x16_f16(ones.h, pa[ks].h, accl, 0, 0, 0);

        __syncthreads();                       // VT_lds reads of tile t done
        if (t < ntile - 1) writeV();
    }

    // ---- epilogue ----
    float lv   = accl[0];
    float linv = lv > 0.f ? 1.0f / lv : 0.f;   // count==0 -> O=0 (matches reference)
    float* orow = O + (qrow0 + q31) * Dd;
#pragma unroll
    for (int dn = 0; dn < 4; ++dn)
#pragma unroll
        for (int rg = 0; rg < 4; ++rg) {
            f32x4 o;
            o[0] = acco[dn][rg * 4 + 0] * linv;
            o[1] = acco[dn][rg * 4 + 1] * linv;
            o[2] = acco[dn][rg * 4 + 2] * linv;
            o[3] = acco[dn][rg * 4 + 3] * linv;
            *(f32x4*)(orow + dn * 32 + rg * 8 + 4 * hi) = o;
        }
}

// ---------------- fallback: verbatim R5 (used if workspace too small) ----------------
__global__ __launch_bounds__(256) __attribute__((amdgpu_waves_per_eu(2, 2)))
void attn_fwd(const float* __restrict__ Q,
              const float* __restrict__ K,
              const float* __restrict__ V,
              const int* __restrict__ M,
              float* __restrict__ O) {
    __shared__ unsigned short K_lds[KVB * 128];
    __shared__ unsigned short VT_lds[128 * 64];
    __shared__ float maskadd[KVB];

    const int tid = threadIdx.x;
    const int w   = tid >> 6;
    const int l   = tid & 63;
    const int q31 = l & 31;
    const int hi  = l >> 5;

    const int bid   = blockIdx.x;
    const int batch = (bid & 7) * 4 + (bid >> 7);
    const int qtile = (bid >> 3) & 15;

    const size_t qrow0  = (size_t)batch * Ss + qtile * 128 + w * 32;
    const size_t kvbase = (size_t)batch * Ss * Dd;
    const size_t mbase  = (size_t)batch * Ss;

    const int krow = tid >> 4;
    const int kcol = (tid & 15) << 3;
    const int vi   = tid & 15;
    const int vk   = (tid >> 4) << 2;

    f32x4 ka[4], kb[4];
    f32x2 vv[4][4];
    int mld = 0;

    auto issueK = [&](int kv) {
#pragma unroll
        for (int it = 0; it < 4; ++it) {
            const float* s = K + kvbase + (size_t)(kv + krow + it * 16) * Dd + kcol;
            ka[it] = *(const f32x4*)s;
            kb[it] = *(const f32x4*)(s + 4);
        }
        if (tid < KVB) mld = M[mbase + kv + tid];
    };
    auto writeK = [&]() {
#pragma unroll
        for (int it = 0; it < 4; ++it) {
            int row = krow + it * 16;
            F16_8 t;
            t.w[0] = pk2(ka[it][0], ka[it][1]);
            t.w[1] = pk2(ka[it][2], ka[it][3]);
            t.w[2] = pk2(kb[it][0], kb[it][1]);
            t.w[3] = pk2(kb[it][2], kb[it][3]);
            *(u16x8*)&K_lds[(row * 128 + kcol) ^ ((row & 7) << 3)] = t.u;
        }
        if (tid < KVB) maskadd[tid] = mld ? 0.f : -1e30f;
    };
    auto issueV = [&](int kv) {
#pragma unroll
        for (int j = 0; j < 4; ++j)
#pragma unroll
            for (int ko = 0; ko < 4; ++ko)
                vv[j][ko] = *(const f32x2*)(V + kvbase + (size_t)(kv + vk + ko) * Dd + 2 * vi + 32 * j);
    };
    auto writeV = [&]() {
#pragma unroll
        for (int j = 0; j < 4; ++j)
#pragma unroll
            for (int p = 0; p < 2; ++p) {
                int row = 2 * vi + p + 32 * j;
                F16_4 t;
                t.w[0] = pk2(vv[j][0][p], vv[j][1][p]);
                t.w[1] = pk2(vv[j][2][p], vv[j][3][p]);
                *(u16x4*)&VT_lds[row * 64 + (vk ^ ((row & 7) << 3))] = t.u;
            }
    };

    F16_8 ones;
    {
        uint32_t ow = (q31 < 8) ? 0x3C003C00u : 0u;
        ones.w[0] = ow; ones.w[1] = ow; ones.w[2] = ow; ones.w[3] = ow;
    }

    const f32x16 z16 = {0,0,0,0,0,0,0,0,0,0,0,0,0,0,0,0};
    f32x16 acco[4];
#pragma unroll
    for (int dn = 0; dn < 4; ++dn) acco[dn] = z16;
    f32x16 accl = z16;
    float mrun = -1e4f;

    const float LOG2E = 1.44269504088896340736f;
    issueK(0); issueV(0);
    F16_8 qf[8];
#pragma unroll
    for (int ks = 0; ks < 8; ++ks) {
        const float* s = Q + (qrow0 + q31) * Dd + ks * 16 + hi * 8;
        f32x4 a = *(const f32x4*)s;
        f32x4 b = *(const f32x4*)(s + 4);
        qf[ks].w[0] = pk2(a[0] * LOG2E, a[1] * LOG2E);
        qf[ks].w[1] = pk2(a[2] * LOG2E, a[3] * LOG2E);
        qf[ks].w[2] = pk2(b[0] * LOG2E, b[1] * LOG2E);
        qf[ks].w[3] = pk2(b[2] * LOG2E, b[3] * LOG2E);
    }
    writeK(); writeV();
    __syncthreads();

    for (int t = 0; t < NIT; ++t) {
        if (t < NIT - 1) issueK((t + 1) * KVB);

        f32x16 accs[2];
        accs[0] = z16; accs[1] = z16;
#pragma unroll
        for (int ks = 0; ks < 8; ++ks) {
#pragma unroll
            for (int n = 0; n < 2; ++n) {
                int row = n * 32 + q31;
                F16_8 kf;
                kf.u = *(const u16x8*)&K_lds[(row * 128 + ks * 16 + hi * 8) ^ ((row & 7) << 3)];
                accs[n] = __builtin_amdgcn_mfma_f32_32x32x16_f16(kf.h, qf[ks].h, accs[n], 0, 0, 0);
            }
        }

#pragma unroll
        for (int n = 0; n < 2; ++n)
#pragma unroll
            for (int blk = 0; blk < 4; ++blk) {
                f32x4 md = *(const f32x4*)&maskadd[n * 32 + blk * 8 + 4 * hi];
#pragma unroll
                for (int r = 0; r < 4; ++r) accs[n][blk * 4 + r] += md[r];
            }

        float mx[16];
#pragma unroll
        for (int i = 0; i < 16; ++i) mx[i] = fmaxf(accs[0][i], accs[1][i]);
#pragma unroll
        for (int s = 8; s >= 1; s >>= 1)
#pragma unroll
            for (int i = 0; i < s; ++i) mx[i] = fmaxf(mx[i], mx[i + s]);
        float pmax = fmaxf(mx[0], __shfl_xor(mx[0], 32));

        if (!__all(pmax - mrun <= 11.5409f)) {
            float mnew = fmaxf(mrun, pmax);
            float sc = __builtin_amdgcn_exp2f(mrun - mnew);
#pragma unroll
            for (int dn = 0; dn < 4; ++dn)
#pragma unroll
                for (int i = 0; i < 16; ++i) acco[dn][i] *= sc;
            accl[0] *= sc;
            mrun = mnew;
        }

#pragma unroll
        for (int n = 0; n < 2; ++n)
#pragma unroll
            for (int i = 0; i < 16; ++i) accs[n][i] = __builtin_amdgcn_exp2f(accs[n][i] - mrun);

        F16_8 pa[4];
#pragma unroll
        for (int ks = 0; ks < 4; ++ks) {
            int n  = ks >> 1;
            int b4 = (ks & 1) * 8;
            uint32_t x0 = pk2(accs[n][b4 + 0], accs[n][b4 + 1]);
            uint32_t x1 = pk2(accs[n][b4 + 2], accs[n][b4 + 3]);
            uint32_t y0 = pk2(accs[n][b4 + 4], accs[n][b4 + 5]);
            uint32_t y1 = pk2(accs[n][b4 + 6], accs[n][b4 + 7]);
            asm volatile("v_permlane32_swap_b32 %0, %1" : "+v"(x0), "+v"(y0));
            asm volatile("v_permlane32_swap_b32 %0, %1" : "+v"(x1), "+v"(y1));
            pa[ks].w[0] = x0; pa[ks].w[1] = x1; pa[ks].w[2] = y0; pa[ks].w[3] = y1;
        }

        __syncthreads();
        if (t < NIT - 1) { writeK(); issueV((t + 1) * KVB); }

#pragma unroll
        for (int dn = 0; dn < 4; ++dn) {
            int row = dn * 32 + q31;
#pragma unroll
            for (int ks = 0; ks < 4; ++ks) {
                F16_8 vf;
                vf.u = *(const u16x8*)&VT_lds[row * 64 + ((ks * 16 + hi * 8) ^ ((row & 7) << 3))];
                acco[dn] = __builtin_amdgcn_mfma_f32_32x32x16_f16(vf.h, pa[ks].h, acco[dn], 0, 0, 0);
            }
        }
#pragma unroll
        for (int ks = 0; ks < 4; ++ks)
            accl = __builtin_amdgcn_mfma_f32_32x32x16_f16(ones.h, pa[ks].h, accl, 0, 0, 0);

        __syncthreads();
        if (t < NIT - 1) writeV();
    }

    float lv   = accl[0];
    float linv = lv > 0.f ? 1.0f / lv : 0.f;
    float* orow = O + (qrow0 + q31) * Dd;
#pragma unroll
    for (int dn = 0; dn < 4; ++dn)
#pragma unroll
        for (int rg = 0; rg < 4; ++rg) {
            f32x4 o;
            o[0] = acco[dn][rg * 4 + 0] * linv;
            o[1] = acco[dn][rg * 4 + 1] * linv;
            o[2] = acco[dn][rg * 4 + 2] * linv;
            o[3] = acco[dn][rg * 4 + 3] * linv;
            *(f32x4*)(orow + dn * 32 + rg * 8 + 4 * hi) = o;
        }
}

extern "C" void kernel_launch(void* const* d_in, const int* in_sizes, int n_in,
                              void* d_out, int out_size, void* d_ws, size_t ws_size,
                              hipStream_t stream) {
    const float* Q = (const float*)d_in[0];
    const float* K = (const float*)d_in[1];
    const float* V = (const float*)d_in[2];
    const int*   M = (const int*)d_in[3];
    float* O = (float*)d_out;

    const size_t nKV   = (size_t)Bb * Ss * Dd;                 // elems per compacted array
    const size_t need  = nKV * 2 * 2 + (size_t)Bb * Ss * 4 + Bb * 4;

    if (d_ws != nullptr && ws_size >= need) {
        unsigned short* Kc   = (unsigned short*)d_ws;
        unsigned short* Vc   = Kc + nKV;
        int*            IDXg = (int*)(Vc + nKV);
        int*            CNT  = IDXg + (size_t)Bb * Ss;
        attn_compact_idx<<<dim3(Bb), dim3(256), 0, stream>>>(M, IDXg, CNT);
        attn_compact_copy<<<dim3(Bb * 32), dim3(256), 0, stream>>>(K, V, IDXg, CNT, Kc, Vc);
        attn_fwd_c<<<dim3(Bb * (Ss / 128)), dim3(256), 0, stream>>>(Q, Kc, Vc, CNT, O);
    } else {
        attn_fwd<<<dim3(Bb * (Ss / 128)), dim3(256), 0, stream>>>(Q, K, V, M, O);
    }
}